// Round 1
// baseline (403.746 us; speedup 1.0000x reference)
//
#include <hip/hip_runtime.h>
#include <hip/hip_bf16.h>
#include <stdint.h>

// Problem: B=8192, D=1024, U=1024.
// z = [x|h] @ Wcat + b, Wcat[k, n] with n = u*4 + g (gate-interleaved), k in [0,2048)
// GEMM: M=8192, N=4096, K=2048, bf16 inputs, fp32 accum, fused LSTM epilogue.

#define MM 8192
#define KK 2048
#define NN 4096
#define BM 128
#define BN 128
#define BK 32

typedef __attribute__((ext_vector_type(8))) __bf16 bf16x8;
typedef __attribute__((ext_vector_type(4))) float floatx4;

__device__ __forceinline__ unsigned short f2bf(float f) {
    unsigned int u = __float_as_uint(f);
    u += 0x7FFF + ((u >> 16) & 1);   // RNE; inputs are finite
    return (unsigned short)(u >> 16);
}

__device__ __forceinline__ float fast_sigmoid(float x) {
    return 1.0f / (1.0f + __expf(-x));
}

__device__ __forceinline__ float fast_tanh(float x) {
    float ax = fabsf(x);
    float e = __expf(-2.0f * ax);
    float t = (1.0f - e) / (1.0f + e);
    return copysignf(t, x);
}

__device__ __forceinline__ void async_copy16(const void* g, void* l) {
    __builtin_amdgcn_global_load_lds(
        (const __attribute__((address_space(1))) void*)g,
        (__attribute__((address_space(3))) void*)l,
        16, 0, 0);
}

// ---------------- pack x|h -> bf16 A[8192][2048] ----------------
__global__ void pack_A(const float* __restrict__ x, const float* __restrict__ h,
                       unsigned short* __restrict__ A) {
    int t = blockIdx.x * 256 + threadIdx.x;      // 4 elements per thread
    long base = (long)t * 4;
    int row = (int)(base >> 11);
    int col = (int)(base & 2047);
    const float* src = (col < 1024) ? (x + (long)row * 1024 + col)
                                    : (h + (long)row * 1024 + (col - 1024));
    float4 v = *(const float4*)src;
    ushort4 o = make_ushort4(f2bf(v.x), f2bf(v.y), f2bf(v.z), f2bf(v.w));
    *(ushort4*)(A + base) = o;
}

// ---------------- pack/transpose weights -> bf16 Wt[4096][2048] ----------------
// Wt[row n = u*4+g][k] : k<1024 -> W_g[k][u], k>=1024 -> U_g[k-1024][u]
__global__ void pack_W(const float* __restrict__ Wi, const float* __restrict__ Wf,
                       const float* __restrict__ Wc, const float* __restrict__ Wo,
                       const float* __restrict__ Ui, const float* __restrict__ Uf,
                       const float* __restrict__ Uc, const float* __restrict__ Uo,
                       unsigned short* __restrict__ Wt) {
    __shared__ float tile[64][65];
    int z = blockIdx.z;                          // 0..7: Wi..Wo, Ui..Uo
    const float* src;
    switch (z) {
        case 0: src = Wi; break; case 1: src = Wf; break;
        case 2: src = Wc; break; case 3: src = Wo; break;
        case 4: src = Ui; break; case 5: src = Uf; break;
        case 6: src = Uc; break; default: src = Uo; break;
    }
    int g = z & 3;
    int koff = (z >= 4) ? 1024 : 0;
    int d0 = blockIdx.x * 64;
    int u0 = blockIdx.y * 64;
    int tid = threadIdx.x;

    int j = tid & 63;
    int ib = tid >> 6;                            // 0..3
#pragma unroll
    for (int p = 0; p < 16; ++p) {
        int i = p * 4 + ib;
        tile[i][j] = src[(long)(d0 + i) * 1024 + u0 + j];
    }
    __syncthreads();
    int i2 = (tid & 31) * 2;
    int jb = tid >> 5;                            // 0..7
#pragma unroll
    for (int p = 0; p < 8; ++p) {
        int j2 = p * 8 + jb;
        unsigned short a = f2bf(tile[i2][j2]);
        unsigned short b = f2bf(tile[i2 + 1][j2]);
        long orow = (long)((u0 + j2) * 4 + g);
        *(ushort2*)(Wt + orow * 2048 + koff + d0 + i2) = make_ushort2(a, b);
    }
}

// ---------------- fused GEMM + LSTM epilogue ----------------
// grid (64, 32): blockIdx.x -> M tile, blockIdx.y -> N tile (32 u's per block)
__global__ __launch_bounds__(256) void lstm_gemm(
    const unsigned short* __restrict__ A,    // [8192][2048] bf16
    const unsigned short* __restrict__ Wt,   // [4096][2048] bf16 (row n = u*4+g)
    const float* __restrict__ c_in,
    const float* __restrict__ Vi, const float* __restrict__ Vf, const float* __restrict__ Vo,
    const float* __restrict__ bi_p, const float* __restrict__ bf_p,
    const float* __restrict__ bc_p, const float* __restrict__ bo_p,
    float* __restrict__ out) {
    // LDS: staging As[128][32] (8KB) + Bs[128][32] (8KB) = 16KB;
    // epilogue reuses it as 4 waves x 16x68 fp32 (17408 B total)
    __shared__ __align__(16) char smem[17408];
    unsigned short* As = (unsigned short*)smem;
    unsigned short* Bs = (unsigned short*)(smem + 8192);

    int tid = threadIdx.x;
    int wave = tid >> 6;
    int lane = tid & 63;
    int wm = wave >> 1, wn = wave & 1;
    int rm0 = blockIdx.x * BM;
    int cn0 = blockIdx.y * BN;

    // staging: per wave, 2 x 1KB chunks each for A and B
    int r_s = wave * 32 + (lane >> 2);          // global-row offset within tile (j=0)
    int kc = (lane & 3) * 8;                    // element offset within 32-wide k chunk
    const unsigned short* gA = A + (long)(rm0 + r_s) * 2048 + kc;
    const unsigned short* gB = Wt + (long)(cn0 + r_s) * 2048 + kc;
    char* ldsA = smem + wave * 2048;            // wave-uniform base; HW adds lane*16
    char* ldsB = smem + 8192 + wave * 2048;

    // fragment read coords (A[m=lane&15][k=quad*8+j], B^T same pattern)
    int fr = lane & 15;
    int fq = (lane >> 4) * 8;

    floatx4 acc[4][4];
#pragma unroll
    for (int i = 0; i < 4; ++i)
#pragma unroll
        for (int j = 0; j < 4; ++j) acc[i][j] = (floatx4)(0.0f);

    for (int kt = 0; kt < KK / BK; ++kt) {
        int k0 = kt * BK;
        async_copy16(gA + k0, ldsA);
        async_copy16(gA + 16 * 2048 + k0, ldsA + 1024);
        async_copy16(gB + k0, ldsB);
        async_copy16(gB + 16 * 2048 + k0, ldsB + 1024);
        __syncthreads();

        bf16x8 af[4], bfr[4];
#pragma unroll
        for (int mi = 0; mi < 4; ++mi)
            af[mi] = *(const bf16x8*)(As + (wm * 64 + mi * 16 + fr) * 32 + fq);
#pragma unroll
        for (int ni = 0; ni < 4; ++ni)
            bfr[ni] = *(const bf16x8*)(Bs + (wn * 64 + ni * 16 + fr) * 32 + fq);
#pragma unroll
        for (int mi = 0; mi < 4; ++mi)
#pragma unroll
            for (int ni = 0; ni < 4; ++ni)
                acc[mi][ni] = __builtin_amdgcn_mfma_f32_16x16x32_bf16(
                    af[mi], bfr[ni], acc[mi][ni], 0, 0, 0);
        __syncthreads();
    }

    // -------- fused epilogue --------
    // wave's 64 cols = wn*64 .. wn*64+64 cover 16 u's x 4 gates (n = u*4+g).
    // C/D layout: col = lane&15, row = quad*4 + reg.
    float* zs = (float*)(smem) + wave * 1088;    // 16 rows x 68 floats (pad 68)
    int u_loc = lane & 15;
    int u_glob = blockIdx.y * 32 + wn * 16 + u_loc;
    int q = lane >> 4;
    float vVi = Vi[u_glob], vVf = Vf[u_glob], vVo = Vo[u_glob];
    float vbi = bi_p[u_glob], vbf = bf_p[u_glob], vbc = bc_p[u_glob], vbo = bo_p[u_glob];

#pragma unroll
    for (int mi = 0; mi < 4; ++mi) {
        __syncthreads();
#pragma unroll
        for (int ni = 0; ni < 4; ++ni)
#pragma unroll
            for (int r = 0; r < 4; ++r)
                zs[(q * 4 + r) * 68 + ni * 16 + u_loc] = acc[mi][ni][r];
        __syncthreads();
#pragma unroll
        for (int t = 0; t < 4; ++t) {
            int rr = t * 4 + q;
            floatx4 z4 = *(const floatx4*)(zs + rr * 68 + u_loc * 4);
            long row_glob = rm0 + wm * 64 + mi * 16 + rr;
            float cv = c_in[row_glob * 1024 + u_glob];
            float i_t = fast_sigmoid(z4[0] + vbi + vVi * cv);
            float f_t = fast_sigmoid(z4[1] + vbf + vVf * cv);
            float ctl = fast_tanh(z4[2] + vbc);
            float c_t = f_t * cv + i_t * ctl;
            float o_t = fast_sigmoid(z4[3] + vbo + vVo * c_t);
            float h_t = o_t * fast_tanh(c_t);
            out[row_glob * 1024 + u_glob] = h_t;
            out[8388608 + row_glob * 1024 + u_glob] = c_t;
        }
    }
}

extern "C" void kernel_launch(void* const* d_in, const int* in_sizes, int n_in,
                              void* d_out, int out_size, void* d_ws, size_t ws_size,
                              hipStream_t stream) {
    const float* x  = (const float*)d_in[0];
    const float* h  = (const float*)d_in[1];
    const float* c  = (const float*)d_in[2];
    const float* Wi = (const float*)d_in[3];
    const float* Wf = (const float*)d_in[4];
    const float* Wc = (const float*)d_in[5];
    const float* Wo = (const float*)d_in[6];
    const float* Ui = (const float*)d_in[7];
    const float* Uf = (const float*)d_in[8];
    const float* Uc = (const float*)d_in[9];
    const float* Uo = (const float*)d_in[10];
    const float* Vi = (const float*)d_in[11];
    const float* Vf = (const float*)d_in[12];
    const float* Vo = (const float*)d_in[13];
    const float* bi = (const float*)d_in[14];
    const float* bf = (const float*)d_in[15];
    const float* bc = (const float*)d_in[16];
    const float* bo = (const float*)d_in[17];

    unsigned short* Abf = (unsigned short*)d_ws;                          // 32 MB
    unsigned short* Wt  = (unsigned short*)((char*)d_ws + 33554432);      // 16 MB

    pack_A<<<dim3(16384), 256, 0, stream>>>(x, h, Abf);
    pack_W<<<dim3(16, 16, 8), 256, 0, stream>>>(Wi, Wf, Wc, Wo, Ui, Uf, Uc, Uo, Wt);
    lstm_gemm<<<dim3(64, 32), 256, 0, stream>>>(Abf, Wt, c, Vi, Vf, Vo,
                                                bi, bf, bc, bo, (float*)d_out);
}

// Round 2
// 352.348 us; speedup vs baseline: 1.1459x; 1.1459x over previous
//
#include <hip/hip_runtime.h>
#include <hip/hip_bf16.h>
#include <stdint.h>

// Problem: B=8192, D=1024, U=1024.
// z = [x|h] @ Wcat + b, Wcat[k, n] with n = u*4 + g (gate-interleaved), k in [0,2048)
// GEMM: M=8192, N=4096, K=2048, bf16 inputs, fp32 accum, fused LSTM epilogue.

#define MM 8192
#define KK 2048
#define NN 4096
#define BM 128
#define BN 128
#define BK 64

typedef __attribute__((ext_vector_type(8))) __bf16 bf16x8;
typedef __attribute__((ext_vector_type(4))) float floatx4;
typedef __attribute__((ext_vector_type(8))) unsigned short ushort8_t;

__device__ __forceinline__ unsigned short f2bf(float f) {
    unsigned int u = __float_as_uint(f);
    u += 0x7FFF + ((u >> 16) & 1);   // RNE; inputs are finite
    return (unsigned short)(u >> 16);
}

__device__ __forceinline__ float fast_sigmoid(float x) {
    return 1.0f / (1.0f + __expf(-x));
}

__device__ __forceinline__ float fast_tanh(float x) {
    float ax = fabsf(x);
    float e = __expf(-2.0f * ax);
    float t = (1.0f - e) / (1.0f + e);
    return copysignf(t, x);
}

__device__ __forceinline__ void async_copy16(const void* g, void* l) {
    __builtin_amdgcn_global_load_lds(
        (const __attribute__((address_space(1))) void*)g,
        (__attribute__((address_space(3))) void*)l,
        16, 0, 0);
}

// ---------------- pack x|h -> bf16 A[8192][2048] ----------------
__global__ void pack_A(const float* __restrict__ x, const float* __restrict__ h,
                       unsigned short* __restrict__ A) {
    int t = blockIdx.x * 256 + threadIdx.x;      // 8 elements per thread
    long base = (long)t * 8;
    int row = (int)(base >> 11);
    int col = (int)(base & 2047);
    const float* src = (col < 1024) ? (x + (long)row * 1024 + col)
                                    : (h + (long)row * 1024 + (col - 1024));
    float4 v0 = *(const float4*)src;
    float4 v1 = *(const float4*)(src + 4);
    ushort8_t o;
    o[0] = f2bf(v0.x); o[1] = f2bf(v0.y); o[2] = f2bf(v0.z); o[3] = f2bf(v0.w);
    o[4] = f2bf(v1.x); o[5] = f2bf(v1.y); o[6] = f2bf(v1.z); o[7] = f2bf(v1.w);
    *(ushort8_t*)(A + base) = o;
}

// ---------------- pack/transpose weights -> bf16 Wt[4096][2048] ----------------
// Wt[row n = u*4+g][k] : k<1024 -> W_g[k][u], k>=1024 -> U_g[k-1024][u]
__global__ void pack_W(const float* __restrict__ Wi, const float* __restrict__ Wf,
                       const float* __restrict__ Wc, const float* __restrict__ Wo,
                       const float* __restrict__ Ui, const float* __restrict__ Uf,
                       const float* __restrict__ Uc, const float* __restrict__ Uo,
                       unsigned short* __restrict__ Wt) {
    __shared__ float tile[64][65];
    int z = blockIdx.z;                          // 0..7: Wi..Wo, Ui..Uo
    const float* src;
    switch (z) {
        case 0: src = Wi; break; case 1: src = Wf; break;
        case 2: src = Wc; break; case 3: src = Wo; break;
        case 4: src = Ui; break; case 5: src = Uf; break;
        case 6: src = Uc; break; default: src = Uo; break;
    }
    int g = z & 3;
    int koff = (z >= 4) ? 1024 : 0;
    int d0 = blockIdx.x * 64;
    int u0 = blockIdx.y * 64;
    int tid = threadIdx.x;

    int j = tid & 63;
    int ib = tid >> 6;                            // 0..3
#pragma unroll
    for (int p = 0; p < 16; ++p) {
        int i = p * 4 + ib;
        tile[i][j] = src[(long)(d0 + i) * 1024 + u0 + j];
    }
    __syncthreads();
    int i2 = (tid & 31) * 2;
    int jb = tid >> 5;                            // 0..7
#pragma unroll
    for (int p = 0; p < 8; ++p) {
        int j2 = p * 8 + jb;
        unsigned short a = f2bf(tile[i2][j2]);
        unsigned short b = f2bf(tile[i2 + 1][j2]);
        long orow = (long)((u0 + j2) * 4 + g);
        *(ushort2*)(Wt + orow * 2048 + koff + d0 + i2) = make_ushort2(a, b);
    }
}

// ---------------- fused GEMM + LSTM epilogue ----------------
// grid 2048 linear; swizzled to 8-wide M supergroups for XCD-L2 A reuse.
// LDS layout (BK=64): As[128][64] bf16 (16KB) + Bs[128][64] (16KB), XOR-swizzled:
//   chunk slot c' = c ^ (row & 7), chunk = 16B (8 bf16), row stride = 128B.
__global__ __launch_bounds__(256) void lstm_gemm(
    const unsigned short* __restrict__ A,    // [8192][2048] bf16
    const unsigned short* __restrict__ Wt,   // [4096][2048] bf16 (row n = u*4+g)
    const float* __restrict__ c_in,
    const float* __restrict__ Vi, const float* __restrict__ Vf, const float* __restrict__ Vo,
    const float* __restrict__ bi_p, const float* __restrict__ bf_p,
    const float* __restrict__ bc_p, const float* __restrict__ bo_p,
    float* __restrict__ out) {
    __shared__ __align__(16) char smem[32768];
    unsigned short* As = (unsigned short*)smem;
    unsigned short* Bs = (unsigned short*)(smem + 16384);

    int tid = threadIdx.x;
    int wave = tid >> 6;
    int lane = tid & 63;
    int wm = wave >> 1, wn = wave & 1;

    int id = blockIdx.x;
    int by = (id >> 3) & 31;                      // N tile
    int bx = (id & 7) | ((id >> 8) << 3);         // M tile, 8-wide supergroups
    int rm0 = bx * BM;
    int cn0 = by * BN;

    // staging: per wave 4 chunks of 1KB each for A and B (8 rows x 128B per chunk)
    // swizzle: lane (r_l = lane>>3, s = lane&7) fetches global chunk c = s ^ r_l
    int r_l = lane >> 3;
    int kc = ((lane & 7) ^ r_l) * 8;
    const unsigned short* gA = A + (long)(rm0 + wave * 32 + r_l) * 2048 + kc;
    const unsigned short* gB = Wt + (long)(cn0 + wave * 32 + r_l) * 2048 + kc;
    char* ldsA = smem + wave * 4096;              // wave-uniform base; HW adds lane*16
    char* ldsB = smem + 16384 + wave * 4096;

    // fragment read coords (A[m=lane&15][k=(lane>>4)*8+j])
    int fr = lane & 15;
    int fc = lane >> 4;                           // k-chunk within 32-wide kstep
    int m7 = fr & 7;

    floatx4 acc[4][4];
#pragma unroll
    for (int i = 0; i < 4; ++i)
#pragma unroll
        for (int j = 0; j < 4; ++j) acc[i][j] = (floatx4)(0.0f);

    for (int kt = 0; kt < KK / BK; ++kt) {
        int k0 = kt * BK;
#pragma unroll
        for (int c8 = 0; c8 < 4; ++c8)
            async_copy16(gA + (long)(c8 * 8) * 2048 + k0, ldsA + c8 * 1024);
#pragma unroll
        for (int c8 = 0; c8 < 4; ++c8)
            async_copy16(gB + (long)(c8 * 8) * 2048 + k0, ldsB + c8 * 1024);
        __syncthreads();

#pragma unroll
        for (int ks = 0; ks < 2; ++ks) {
            int sl = ((ks * 4 + fc) ^ m7) * 8;    // swizzled element offset in row
            bf16x8 af[4], bfr[4];
#pragma unroll
            for (int mi = 0; mi < 4; ++mi)
                af[mi] = *(const bf16x8*)(As + (wm * 64 + mi * 16 + fr) * 64 + sl);
#pragma unroll
            for (int ni = 0; ni < 4; ++ni)
                bfr[ni] = *(const bf16x8*)(Bs + (wn * 64 + ni * 16 + fr) * 64 + sl);
#pragma unroll
            for (int mi = 0; mi < 4; ++mi)
#pragma unroll
                for (int ni = 0; ni < 4; ++ni)
                    acc[mi][ni] = __builtin_amdgcn_mfma_f32_16x16x32_bf16(
                        af[mi], bfr[ni], acc[mi][ni], 0, 0, 0);
        }
        __syncthreads();
    }

    // -------- fused epilogue --------
    // wave's 64 cols = 16 u's x 4 gates (n = u*4+g).
    // C/D layout: col = lane&15, row = quad*4 + reg.
    float* zs = (float*)(smem) + wave * 1088;    // 16 rows x 68 floats (pad 68)
    int u_loc = lane & 15;
    int u_glob = by * 32 + wn * 16 + u_loc;
    int q = lane >> 4;
    float vVi = Vi[u_glob], vVf = Vf[u_glob], vVo = Vo[u_glob];
    float vbi = bi_p[u_glob], vbf = bf_p[u_glob], vbc = bc_p[u_glob], vbo = bo_p[u_glob];

#pragma unroll
    for (int mi = 0; mi < 4; ++mi) {
        __syncthreads();
#pragma unroll
        for (int ni = 0; ni < 4; ++ni)
#pragma unroll
            for (int r = 0; r < 4; ++r)
                zs[(q * 4 + r) * 68 + ni * 16 + u_loc] = acc[mi][ni][r];
        __syncthreads();
#pragma unroll
        for (int t = 0; t < 4; ++t) {
            int rr = t * 4 + q;
            floatx4 z4 = *(const floatx4*)(zs + rr * 68 + u_loc * 4);
            long row_glob = rm0 + wm * 64 + mi * 16 + rr;
            float cv = c_in[row_glob * 1024 + u_glob];
            float i_t = fast_sigmoid(z4[0] + vbi + vVi * cv);
            float f_t = fast_sigmoid(z4[1] + vbf + vVf * cv);
            float ctl = fast_tanh(z4[2] + vbc);
            float c_t = f_t * cv + i_t * ctl;
            float o_t = fast_sigmoid(z4[3] + vbo + vVo * c_t);
            float h_t = o_t * fast_tanh(c_t);
            out[row_glob * 1024 + u_glob] = h_t;
            out[8388608 + row_glob * 1024 + u_glob] = c_t;
        }
    }
}

extern "C" void kernel_launch(void* const* d_in, const int* in_sizes, int n_in,
                              void* d_out, int out_size, void* d_ws, size_t ws_size,
                              hipStream_t stream) {
    const float* x  = (const float*)d_in[0];
    const float* h  = (const float*)d_in[1];
    const float* c  = (const float*)d_in[2];
    const float* Wi = (const float*)d_in[3];
    const float* Wf = (const float*)d_in[4];
    const float* Wc = (const float*)d_in[5];
    const float* Wo = (const float*)d_in[6];
    const float* Ui = (const float*)d_in[7];
    const float* Uf = (const float*)d_in[8];
    const float* Uc = (const float*)d_in[9];
    const float* Uo = (const float*)d_in[10];
    const float* Vi = (const float*)d_in[11];
    const float* Vf = (const float*)d_in[12];
    const float* Vo = (const float*)d_in[13];
    const float* bi = (const float*)d_in[14];
    const float* bf = (const float*)d_in[15];
    const float* bc = (const float*)d_in[16];
    const float* bo = (const float*)d_in[17];

    unsigned short* Abf = (unsigned short*)d_ws;                          // 32 MB
    unsigned short* Wt  = (unsigned short*)((char*)d_ws + 33554432);      // 16 MB

    pack_A<<<dim3(8192), 256, 0, stream>>>(x, h, Abf);
    pack_W<<<dim3(16, 16, 8), 256, 0, stream>>>(Wi, Wf, Wc, Wo, Ui, Uf, Uc, Uo, Wt);
    lstm_gemm<<<dim3(2048), 256, 0, stream>>>(Abf, Wt, c, Vi, Vf, Vo,
                                              bi, bf, bc, bo, (float*)d_out);
}

// Round 3
// 343.499 us; speedup vs baseline: 1.1754x; 1.0258x over previous
//
#include <hip/hip_runtime.h>
#include <hip/hip_bf16.h>
#include <stdint.h>

// Problem: B=8192, D=1024, U=1024.
// z = [x|h] @ Wcat + b, Wcat[k, n] with n = u*4 + g (gate-interleaved), k in [0,2048)
// GEMM: M=8192, N=4096, K=2048, bf16 inputs, fp32 accum, fused LSTM epilogue.

#define MM 8192
#define KK 2048
#define NN 4096
#define BM 128
#define BN 128
#define BK 64

typedef __attribute__((ext_vector_type(8))) __bf16 bf16x8;
typedef __attribute__((ext_vector_type(4))) float floatx4;
typedef __attribute__((ext_vector_type(8))) unsigned short ushort8_t;

__device__ __forceinline__ unsigned short f2bf(float f) {
    unsigned int u = __float_as_uint(f);
    u += 0x7FFF + ((u >> 16) & 1);   // RNE; inputs are finite
    return (unsigned short)(u >> 16);
}

__device__ __forceinline__ float fast_sigmoid(float x) {
    return 1.0f / (1.0f + __expf(-x));
}

__device__ __forceinline__ float fast_tanh(float x) {
    float ax = fabsf(x);
    float e = __expf(-2.0f * ax);
    float t = (1.0f - e) / (1.0f + e);
    return copysignf(t, x);
}

__device__ __forceinline__ void async_copy16(const void* g, void* l) {
    __builtin_amdgcn_global_load_lds(
        (const __attribute__((address_space(1))) void*)g,
        (__attribute__((address_space(3))) void*)l,
        16, 0, 0);
}

// ---------------- fused pack kernel ----------------
// blocks [0,2048): transpose weights -> bf16 Wt[4096][2048], row n=u*4+g
// blocks [2048,10240): pack x|h -> bf16 A[8192][2048], 8 elem/thread
__global__ void pack_all(const float* __restrict__ x, const float* __restrict__ h,
                         const float* __restrict__ Wi, const float* __restrict__ Wf,
                         const float* __restrict__ Wc, const float* __restrict__ Wo,
                         const float* __restrict__ Ui, const float* __restrict__ Uf,
                         const float* __restrict__ Uc, const float* __restrict__ Uo,
                         unsigned short* __restrict__ A,
                         unsigned short* __restrict__ Wt) {
    __shared__ float tile[64][65];
    int blk = blockIdx.x;
    int tid = threadIdx.x;
    if (blk >= 2048) {
        // ---- A pack ----
        int t = (blk - 2048) * 256 + tid;
        long base = (long)t * 8;
        int row = (int)(base >> 11);
        int col = (int)(base & 2047);
        const float* src = (col < 1024) ? (x + (long)row * 1024 + col)
                                        : (h + (long)row * 1024 + (col - 1024));
        float4 v0 = *(const float4*)src;
        float4 v1 = *(const float4*)(src + 4);
        ushort8_t o;
        o[0] = f2bf(v0.x); o[1] = f2bf(v0.y); o[2] = f2bf(v0.z); o[3] = f2bf(v0.w);
        o[4] = f2bf(v1.x); o[5] = f2bf(v1.y); o[6] = f2bf(v1.z); o[7] = f2bf(v1.w);
        *(ushort8_t*)(A + base) = o;
        return;
    }
    // ---- W transpose ----
    int z = blk >> 8;                            // 0..7: Wi..Wo, Ui..Uo
    int rem = blk & 255;
    const float* src;
    switch (z) {
        case 0: src = Wi; break; case 1: src = Wf; break;
        case 2: src = Wc; break; case 3: src = Wo; break;
        case 4: src = Ui; break; case 5: src = Uf; break;
        case 6: src = Uc; break; default: src = Uo; break;
    }
    int g = z & 3;
    int koff = (z >= 4) ? 1024 : 0;
    int d0 = (rem >> 4) * 64;
    int u0 = (rem & 15) * 64;

    int j = tid & 63;
    int ib = tid >> 6;                            // 0..3
#pragma unroll
    for (int p = 0; p < 16; ++p) {
        int i = p * 4 + ib;
        tile[i][j] = src[(long)(d0 + i) * 1024 + u0 + j];
    }
    __syncthreads();
    int i2 = (tid & 31) * 2;
    int jb = tid >> 5;                            // 0..7
#pragma unroll
    for (int p = 0; p < 8; ++p) {
        int j2 = p * 8 + jb;
        unsigned short a = f2bf(tile[i2][j2]);
        unsigned short b = f2bf(tile[i2 + 1][j2]);
        long orow = (long)((u0 + j2) * 4 + g);
        *(ushort2*)(Wt + orow * 2048 + koff + d0 + i2) = make_ushort2(a, b);
    }
}

// ---------------- fused GEMM + LSTM epilogue ----------------
// grid 2048 linear, bx = id & 63 (M tile, fast), by = id >> 6 (N tile).
// LDS (BK=64): As[128][64] bf16 (16KB) + Bs[128][64] (16KB), XOR-swizzled:
//   chunk slot c' = c ^ (row & 7), chunk = 16B (8 bf16), row stride = 128B.
__global__ __launch_bounds__(256) void lstm_gemm(
    const unsigned short* __restrict__ A,    // [8192][2048] bf16
    const unsigned short* __restrict__ Wt,   // [4096][2048] bf16 (row n = u*4+g)
    const float* __restrict__ c_in,
    const float* __restrict__ Vi, const float* __restrict__ Vf, const float* __restrict__ Vo,
    const float* __restrict__ bi_p, const float* __restrict__ bf_p,
    const float* __restrict__ bc_p, const float* __restrict__ bo_p,
    float* __restrict__ out) {
    __shared__ __align__(16) char smem[32768];
    unsigned short* As = (unsigned short*)smem;
    unsigned short* Bs = (unsigned short*)(smem + 16384);

    int tid = threadIdx.x;
    int wave = tid >> 6;
    int lane = tid & 63;
    int wm = wave >> 1, wn = wave & 1;

    int id = blockIdx.x;
    int bx = id & 63;                             // M tile (fast)
    int by = id >> 6;                             // N tile
    int rm0 = bx * BM;
    int cn0 = by * BN;

    // staging: per wave 4 chunks of 1KB each for A and B (8 rows x 128B per chunk)
    // swizzle: lane (r_l = lane>>3, s = lane&7) fetches global chunk c = s ^ r_l
    int r_l = lane >> 3;
    int kc = ((lane & 7) ^ r_l) * 8;
    // uniform base + loop-invariant divergent 32-bit offsets (saddr-friendly)
    const unsigned short* gAu = A + (long)rm0 * 2048;
    const unsigned short* gBu = Wt + (long)cn0 * 2048;
    int voff = (wave * 32 + r_l) * 2048 + kc;
    char* ldsA = smem + wave * 4096;              // wave-uniform base; HW adds lane*16
    char* ldsB = smem + 16384 + wave * 4096;

    // fragment read coords (A[m=lane&15][k=(lane>>4)*8+j])
    int fr = lane & 15;
    int fc = lane >> 4;                           // k-chunk within 32-wide kstep
    int m7 = fr & 7;

    floatx4 acc[4][4];
#pragma unroll
    for (int i = 0; i < 4; ++i)
#pragma unroll
        for (int j = 0; j < 4; ++j) acc[i][j] = (floatx4)(0.0f);

    for (int kt = 0; kt < KK / BK; ++kt) {
        int k0 = kt * BK;
        const unsigned short* gAk = gAu + k0;     // uniform advance
        const unsigned short* gBk = gBu + k0;
#pragma unroll
        for (int c8 = 0; c8 < 4; ++c8)
            async_copy16(gAk + voff + c8 * (8 * 2048), ldsA + c8 * 1024);
#pragma unroll
        for (int c8 = 0; c8 < 4; ++c8)
            async_copy16(gBk + voff + c8 * (8 * 2048), ldsB + c8 * 1024);
        __syncthreads();

#pragma unroll
        for (int ks = 0; ks < 2; ++ks) {
            int sl = ((ks * 4 + fc) ^ m7) * 8;    // swizzled element offset in row
            bf16x8 af[4], bfr[4];
#pragma unroll
            for (int mi = 0; mi < 4; ++mi)
                af[mi] = *(const bf16x8*)(As + (wm * 64 + mi * 16 + fr) * 64 + sl);
#pragma unroll
            for (int ni = 0; ni < 4; ++ni)
                bfr[ni] = *(const bf16x8*)(Bs + (wn * 64 + ni * 16 + fr) * 64 + sl);
#pragma unroll
            for (int mi = 0; mi < 4; ++mi)
#pragma unroll
                for (int ni = 0; ni < 4; ++ni)
                    acc[mi][ni] = __builtin_amdgcn_mfma_f32_16x16x32_bf16(
                        af[mi], bfr[ni], acc[mi][ni], 0, 0, 0);
        }
        __syncthreads();
    }

    // -------- fused epilogue (block-level, coalesced) --------
    // Per mi round: all 4 waves dump acc[mi][*] into zs[32 rows][132], where
    // rowL = wm*16 + q*4 + r, col n_within = wn*64 + ni*16 + (lane&15) = u_b*4+g.
    // Then 256 threads process (row, u_b = tid&31) pairs: fully coalesced
    // c_in loads / out stores (128B per half-wave).
    float* zs = (float*)smem;                     // 32*132*4 = 16896 B
    int col = lane & 15;
    int q = lane >> 4;
    int u_b = tid & 31;
    int u_glob = by * 32 + u_b;
    float vVi = Vi[u_glob], vVf = Vf[u_glob], vVo = Vo[u_glob];
    float vbi = bi_p[u_glob], vbf = bf_p[u_glob], vbc = bc_p[u_glob], vbo = bo_p[u_glob];

#pragma unroll
    for (int mi = 0; mi < 4; ++mi) {
        if (mi) __syncthreads();
#pragma unroll
        for (int ni = 0; ni < 4; ++ni)
#pragma unroll
            for (int r = 0; r < 4; ++r)
                zs[(wm * 16 + q * 4 + r) * 132 + wn * 64 + ni * 16 + col] = acc[mi][ni][r];
        __syncthreads();
#pragma unroll
        for (int t = 0; t < 4; ++t) {
            int rowL = (tid >> 5) + t * 8;
            floatx4 z4 = *(const floatx4*)(zs + rowL * 132 + u_b * 4);
            long row_glob = rm0 + (rowL >> 4) * 64 + mi * 16 + (rowL & 15);
            float cv = c_in[row_glob * 1024 + u_glob];
            float i_t = fast_sigmoid(z4[0] + vbi + vVi * cv);
            float f_t = fast_sigmoid(z4[1] + vbf + vVf * cv);
            float ctl = fast_tanh(z4[2] + vbc);
            float c_t = f_t * cv + i_t * ctl;
            float o_t = fast_sigmoid(z4[3] + vbo + vVo * c_t);
            float h_t = o_t * fast_tanh(c_t);
            out[row_glob * 1024 + u_glob] = h_t;
            out[8388608 + row_glob * 1024 + u_glob] = c_t;
        }
    }
}

extern "C" void kernel_launch(void* const* d_in, const int* in_sizes, int n_in,
                              void* d_out, int out_size, void* d_ws, size_t ws_size,
                              hipStream_t stream) {
    const float* x  = (const float*)d_in[0];
    const float* h  = (const float*)d_in[1];
    const float* c  = (const float*)d_in[2];
    const float* Wi = (const float*)d_in[3];
    const float* Wf = (const float*)d_in[4];
    const float* Wc = (const float*)d_in[5];
    const float* Wo = (const float*)d_in[6];
    const float* Ui = (const float*)d_in[7];
    const float* Uf = (const float*)d_in[8];
    const float* Uc = (const float*)d_in[9];
    const float* Uo = (const float*)d_in[10];
    const float* Vi = (const float*)d_in[11];
    const float* Vf = (const float*)d_in[12];
    const float* Vo = (const float*)d_in[13];
    const float* bi = (const float*)d_in[14];
    const float* bf = (const float*)d_in[15];
    const float* bc = (const float*)d_in[16];
    const float* bo = (const float*)d_in[17];

    unsigned short* Abf = (unsigned short*)d_ws;                          // 32 MB
    unsigned short* Wt  = (unsigned short*)((char*)d_ws + 33554432);      // 16 MB

    pack_all<<<dim3(10240), 256, 0, stream>>>(x, h, Wi, Wf, Wc, Wo,
                                              Ui, Uf, Uc, Uo, Abf, Wt);
    lstm_gemm<<<dim3(2048), 256, 0, stream>>>(Abf, Wt, c, Vi, Vf, Vo,
                                              bi, bf, bc, bo, (float*)d_out);
}

// Round 4
// 333.847 us; speedup vs baseline: 1.2094x; 1.0289x over previous
//
#include <hip/hip_runtime.h>
#include <hip/hip_bf16.h>
#include <stdint.h>

// Problem: B=8192, D=1024, U=1024.
// z = [x|h] @ Wcat + b, Wcat[k, n] with n = u*4 + g (gate-interleaved), k in [0,2048)
// GEMM: M=8192, N=4096, K=2048, bf16 inputs, fp32 accum, fused LSTM epilogue.

#define MM 8192
#define KK 2048
#define NN 4096
#define BM 128
#define BN 128
#define BK 64

typedef __attribute__((ext_vector_type(8))) __bf16 bf16x8;
typedef __attribute__((ext_vector_type(4))) float floatx4;
typedef __attribute__((ext_vector_type(8))) unsigned short ushort8_t;

__device__ __forceinline__ unsigned short f2bf(float f) {
    unsigned int u = __float_as_uint(f);
    u += 0x7FFF + ((u >> 16) & 1);   // RNE; inputs are finite
    return (unsigned short)(u >> 16);
}

__device__ __forceinline__ float fast_sigmoid(float x) {
    return 1.0f / (1.0f + __expf(-x));
}

// tanh(x) = 2*sigmoid(2x)-1; exp->inf saturates correctly to -1/+1
__device__ __forceinline__ float fast_tanh(float x) {
    return 2.0f / (1.0f + __expf(-2.0f * x)) - 1.0f;
}

__device__ __forceinline__ void async_copy16(const void* g, void* l) {
    __builtin_amdgcn_global_load_lds(
        (const __attribute__((address_space(1))) void*)g,
        (__attribute__((address_space(3))) void*)l,
        16, 0, 0);
}

// ---------------- fused pack kernel ----------------
// blocks [0,2048): transpose weights -> bf16 Wt[4096][2048], row n=u*4+g
// blocks [2048,10240): pack x|h -> bf16 A[8192][2048], 8 elem/thread
__global__ void pack_all(const float* __restrict__ x, const float* __restrict__ h,
                         const float* __restrict__ Wi, const float* __restrict__ Wf,
                         const float* __restrict__ Wc, const float* __restrict__ Wo,
                         const float* __restrict__ Ui, const float* __restrict__ Uf,
                         const float* __restrict__ Uc, const float* __restrict__ Uo,
                         unsigned short* __restrict__ A,
                         unsigned short* __restrict__ Wt) {
    __shared__ float tile[64][65];
    int blk = blockIdx.x;
    int tid = threadIdx.x;
    if (blk >= 2048) {
        // ---- A pack ----
        int t = (blk - 2048) * 256 + tid;
        long base = (long)t * 8;
        int row = (int)(base >> 11);
        int col = (int)(base & 2047);
        const float* src = (col < 1024) ? (x + (long)row * 1024 + col)
                                        : (h + (long)row * 1024 + (col - 1024));
        float4 v0 = *(const float4*)src;
        float4 v1 = *(const float4*)(src + 4);
        ushort8_t o;
        o[0] = f2bf(v0.x); o[1] = f2bf(v0.y); o[2] = f2bf(v0.z); o[3] = f2bf(v0.w);
        o[4] = f2bf(v1.x); o[5] = f2bf(v1.y); o[6] = f2bf(v1.z); o[7] = f2bf(v1.w);
        *(ushort8_t*)(A + base) = o;
        return;
    }
    // ---- W transpose ----
    int z = blk >> 8;                            // 0..7: Wi..Wo, Ui..Uo
    int rem = blk & 255;
    const float* src;
    switch (z) {
        case 0: src = Wi; break; case 1: src = Wf; break;
        case 2: src = Wc; break; case 3: src = Wo; break;
        case 4: src = Ui; break; case 5: src = Uf; break;
        case 6: src = Uc; break; default: src = Uo; break;
    }
    int g = z & 3;
    int koff = (z >= 4) ? 1024 : 0;
    int d0 = (rem >> 4) * 64;
    int u0 = (rem & 15) * 64;

    int j = tid & 63;
    int ib = tid >> 6;                            // 0..3
#pragma unroll
    for (int p = 0; p < 16; ++p) {
        int i = p * 4 + ib;
        tile[i][j] = src[(long)(d0 + i) * 1024 + u0 + j];
    }
    __syncthreads();
    int i2 = (tid & 31) * 2;
    int jb = tid >> 5;                            // 0..7
#pragma unroll
    for (int p = 0; p < 8; ++p) {
        int j2 = p * 8 + jb;
        unsigned short a = f2bf(tile[i2][j2]);
        unsigned short b = f2bf(tile[i2 + 1][j2]);
        long orow = (long)((u0 + j2) * 4 + g);
        *(ushort2*)(Wt + orow * 2048 + koff + d0 + i2) = make_ushort2(a, b);
    }
}

// ---------------- fused GEMM + LSTM epilogue ----------------
// grid 2048 linear, bx = id & 63 (M tile, fast), by = id >> 6 (N tile).
// LDS (BK=64): As[128][64] bf16 (16KB) + Bs[128][64] (16KB), XOR-swizzled:
//   chunk slot c' = c ^ (row & 7), chunk = 16B (8 bf16), row stride = 128B.
// K-loop fully unrolled: per-iter global offset kt*128B folds into the
// instruction's 13-bit offset field -> zero per-iter address VALU.
__global__ __launch_bounds__(256) void lstm_gemm(
    const unsigned short* __restrict__ A,    // [8192][2048] bf16
    const unsigned short* __restrict__ Wt,   // [4096][2048] bf16 (row n = u*4+g)
    const float* __restrict__ c_in,
    const float* __restrict__ Vi, const float* __restrict__ Vf, const float* __restrict__ Vo,
    const float* __restrict__ bi_p, const float* __restrict__ bf_p,
    const float* __restrict__ bc_p, const float* __restrict__ bo_p,
    float* __restrict__ out) {
    __shared__ __align__(16) char smem[32768];
    unsigned short* As = (unsigned short*)smem;
    unsigned short* Bs = (unsigned short*)(smem + 16384);

    int tid = threadIdx.x;
    int wave = tid >> 6;
    int lane = tid & 63;
    int wm = wave >> 1, wn = wave & 1;

    int id = blockIdx.x;
    int bx = id & 63;                             // M tile (fast)
    int by = id >> 6;                             // N tile
    int rm0 = bx * BM;
    int cn0 = by * BN;

    // staging: per wave 4 chunks of 1KB each for A and B (8 rows x 128B per chunk)
    // swizzle: lane (r_l = lane>>3, s = lane&7) fetches global chunk c = s ^ r_l
    int r_l = lane >> 3;
    int kc = ((lane & 7) ^ r_l) * 8;
    int voff = (wave * 32 + r_l) * 2048 + kc;
    // 8 loop-invariant per-lane base pointers (VGPR pairs, set once)
    const unsigned short* aP0 = A + (long)rm0 * 2048 + voff;
    const unsigned short* aP1 = aP0 + 8 * 2048;
    const unsigned short* aP2 = aP0 + 16 * 2048;
    const unsigned short* aP3 = aP0 + 24 * 2048;
    const unsigned short* bP0 = Wt + (long)cn0 * 2048 + voff;
    const unsigned short* bP1 = bP0 + 8 * 2048;
    const unsigned short* bP2 = bP0 + 16 * 2048;
    const unsigned short* bP3 = bP0 + 24 * 2048;
    char* ldsA = smem + wave * 4096;              // wave-uniform base; HW adds lane*16
    char* ldsB = smem + 16384 + wave * 4096;

    // fragment read coords (A[m=lane&15][k=(lane>>4)*8+j])
    int fr = lane & 15;
    int fc = lane >> 4;                           // k-chunk within 32-wide kstep
    int m7 = fr & 7;

    floatx4 acc[4][4];
#pragma unroll
    for (int i = 0; i < 4; ++i)
#pragma unroll
        for (int j = 0; j < 4; ++j) acc[i][j] = (floatx4)(0.0f);

#pragma unroll
    for (int kt = 0; kt < KK / BK; ++kt) {
        const int k0 = kt * BK;                   // compile-time; 128B steps
        async_copy16(aP0 + k0, ldsA);
        async_copy16(aP1 + k0, ldsA + 1024);
        async_copy16(aP2 + k0, ldsA + 2048);
        async_copy16(aP3 + k0, ldsA + 3072);
        async_copy16(bP0 + k0, ldsB);
        async_copy16(bP1 + k0, ldsB + 1024);
        async_copy16(bP2 + k0, ldsB + 2048);
        async_copy16(bP3 + k0, ldsB + 3072);
        __syncthreads();

#pragma unroll
        for (int ks = 0; ks < 2; ++ks) {
            int sl = ((ks * 4 + fc) ^ m7) * 8;    // swizzled element offset in row
            bf16x8 af[4], bfr[4];
#pragma unroll
            for (int mi = 0; mi < 4; ++mi)
                af[mi] = *(const bf16x8*)(As + (wm * 64 + mi * 16 + fr) * 64 + sl);
#pragma unroll
            for (int ni = 0; ni < 4; ++ni)
                bfr[ni] = *(const bf16x8*)(Bs + (wn * 64 + ni * 16 + fr) * 64 + sl);
#pragma unroll
            for (int mi = 0; mi < 4; ++mi)
#pragma unroll
                for (int ni = 0; ni < 4; ++ni)
                    acc[mi][ni] = __builtin_amdgcn_mfma_f32_16x16x32_bf16(
                        af[mi], bfr[ni], acc[mi][ni], 0, 0, 0);
        }
        __syncthreads();
    }

    // -------- fused epilogue (block-level, coalesced) --------
    // Per mi round: all 4 waves dump acc[mi][*] into zs[32 rows][132], where
    // rowL = wm*16 + q*4 + r, col n_within = wn*64 + ni*16 + (lane&15) = u_b*4+g.
    // Then 256 threads process (row, u_b = tid&31) pairs: fully coalesced
    // c_in loads / out stores (128B per half-wave).
    float* zs = (float*)smem;                     // 32*132*4 = 16896 B
    int col = lane & 15;
    int q = lane >> 4;
    int u_b = tid & 31;
    int u_glob = by * 32 + u_b;
    float vVi = Vi[u_glob], vVf = Vf[u_glob], vVo = Vo[u_glob];
    float vbi = bi_p[u_glob], vbf = bf_p[u_glob], vbc = bc_p[u_glob], vbo = bo_p[u_glob];

#pragma unroll
    for (int mi = 0; mi < 4; ++mi) {
        if (mi) __syncthreads();
#pragma unroll
        for (int ni = 0; ni < 4; ++ni)
#pragma unroll
            for (int r = 0; r < 4; ++r)
                zs[(wm * 16 + q * 4 + r) * 132 + wn * 64 + ni * 16 + col] = acc[mi][ni][r];
        __syncthreads();
#pragma unroll
        for (int t = 0; t < 4; ++t) {
            int rowL = (tid >> 5) + t * 8;
            floatx4 z4 = *(const floatx4*)(zs + rowL * 132 + u_b * 4);
            long row_glob = rm0 + (rowL >> 4) * 64 + mi * 16 + (rowL & 15);
            float cv = c_in[row_glob * 1024 + u_glob];
            float i_t = fast_sigmoid(z4[0] + vbi + vVi * cv);
            float f_t = fast_sigmoid(z4[1] + vbf + vVf * cv);
            float ctl = fast_tanh(z4[2] + vbc);
            float c_t = f_t * cv + i_t * ctl;
            float o_t = fast_sigmoid(z4[3] + vbo + vVo * c_t);
            float h_t = o_t * fast_tanh(c_t);
            out[row_glob * 1024 + u_glob] = h_t;
            out[8388608 + row_glob * 1024 + u_glob] = c_t;
        }
    }
}

extern "C" void kernel_launch(void* const* d_in, const int* in_sizes, int n_in,
                              void* d_out, int out_size, void* d_ws, size_t ws_size,
                              hipStream_t stream) {
    const float* x  = (const float*)d_in[0];
    const float* h  = (const float*)d_in[1];
    const float* c  = (const float*)d_in[2];
    const float* Wi = (const float*)d_in[3];
    const float* Wf = (const float*)d_in[4];
    const float* Wc = (const float*)d_in[5];
    const float* Wo = (const float*)d_in[6];
    const float* Ui = (const float*)d_in[7];
    const float* Uf = (const float*)d_in[8];
    const float* Uc = (const float*)d_in[9];
    const float* Uo = (const float*)d_in[10];
    const float* Vi = (const float*)d_in[11];
    const float* Vf = (const float*)d_in[12];
    const float* Vo = (const float*)d_in[13];
    const float* bi = (const float*)d_in[14];
    const float* bf = (const float*)d_in[15];
    const float* bc = (const float*)d_in[16];
    const float* bo = (const float*)d_in[17];

    unsigned short* Abf = (unsigned short*)d_ws;                          // 32 MB
    unsigned short* Wt  = (unsigned short*)((char*)d_ws + 33554432);      // 16 MB

    pack_all<<<dim3(10240), 256, 0, stream>>>(x, h, Wi, Wf, Wc, Wo,
                                              Ui, Uf, Uc, Uo, Abf, Wt);
    lstm_gemm<<<dim3(2048), 256, 0, stream>>>(Abf, Wt, c, Vi, Vf, Vo,
                                              bi, bf, bc, bo, (float*)d_out);
}